// Round 1
// 21.098 us; speedup vs baseline: 1.0333x; 1.0333x over previous
//
#include <hip/hip_runtime.h>

#define KNBR 32
#define G 8
#define OBS 16
#define KP 4          // neighbors per thread
#define TPQ 8         // threads per query
#define BLOCK 256

__global__ __launch_bounds__(BLOCK, 8) void gib_kernel(
    const float* __restrict__ points,
    const float* __restrict__ q_coords,
    const int*   __restrict__ sidx,
    const float* __restrict__ cy_radius,
    const float* __restrict__ disk_radius,
    const float* __restrict__ disk_width,
    const float* __restrict__ cone_radius,
    const float* __restrict__ cone_inc,
    const float* __restrict__ ellip_radii,
    const float* __restrict__ lambdas,
    float* __restrict__ out,
    int M)
{
    // per-g params packed for one ds_read_b128 pair:
    // [g][0..7] = ccy, inc, ccn, da, db, e_xy, e_xx, e_zz
    __shared__ float s_par[G * 8];
    __shared__ float s_lam[4 * G * OBS];   // (32,16) row-major

    const float NL2E = -0.5f * 1.44269504088896340736f;
    const float EPS  = 1e-8f;

    const int t = threadIdx.x;
    if (t < G) {
        float r;
        r = cy_radius[t];        s_par[t*8 + 0] = NL2E / (r*r + EPS);
        s_par[t*8 + 1] = cone_inc[t];
        r = cone_radius[t];      s_par[t*8 + 2] = NL2E / (r*r + EPS);
        r = disk_radius[t];      s_par[t*8 + 3] = NL2E / (r*r + EPS);
        r = disk_width[t];       s_par[t*8 + 4] = NL2E / (r*r + EPS);
        float ra = ellip_radii[3*t+0];
        float rb = ellip_radii[3*t+1];
        float rc = ellip_radii[3*t+2];
        float ea = NL2E / (ra*ra + EPS);
        float eb = NL2E / (rb*rb + EPS);
        float ec = NL2E / (rc*rc + EPS);
        // x2*ea + y2*eb + z2*ec == xy2*eb + x2*(ea-eb) + z2*ec
        s_par[t*8 + 5] = eb;        // coeff of xy2
        s_par[t*8 + 6] = ea - eb;   // coeff of x2
        s_par[t*8 + 7] = ec;        // coeff of z2
    }
    s_lam[t]       = lambdas[t];
    s_lam[t + 256] = lambdas[t + 256];
    __syncthreads();

    const int gid = blockIdx.x * BLOCK + t;
    const int m   = gid >> 3;       // query index
    const int sub = t & 7;          // which eighth of K / which column pair
    if (m >= M) return;

    const float qx = q_coords[3*m + 0];
    const float qy = q_coords[3*m + 1];
    const float qz = q_coords[3*m + 2];

    // 4 neighbor indices: one int4 (8 lanes cover 128B contiguous per query)
    const int4 iv = *(const int4*)(sidx + (size_t)m * KNBR + sub * KP);
    const int id[KP] = {iv.x, iv.y, iv.z, iv.w};

    float x2[KP], z2[KP], xy2[KP], rxy[KP], zz[KP];
    const float INF = __builtin_inff();
    #pragma unroll
    for (int j = 0; j < KP; j++) {
        const float* p = points + 3*(size_t)id[j];
        float rx = p[0]-qx, ry = p[1]-qy, rz = p[2]-qz;
        float a = rx*rx, b = ry*ry, c = rz*rz;
        bool act = (a + b + c <= 1.0f);      // REACH^2 = 1
        // masked neighbor: drive exp2 args to -inf -> weight exactly 0.
        // x2 must be 0 (not INF): its coeff (ea-eb) can be positive -> NaN risk;
        // xy2=INF (negative coeff) already forces the ellip arg to -inf.
        x2[j]  = act ? a : 0.0f;
        z2[j]  = act ? c : INF;
        xy2[j] = act ? (a+b) : INF;
        rxy[j] = act ? __builtin_amdgcn_sqrtf(a+b+EPS) : INF;
        zz[j]  = rz;
    }

    float o0 = 0.f, o1 = 0.f;
    const float2* lamp = (const float2*)s_lam + sub;   // row stride = 8 float2

    #pragma unroll
    for (int g = 0; g < G; g++) {
        const float4 pA = *(const float4*)(s_par + g*8);     // ccy,inc,ccn,da
        const float4 pB = *(const float4*)(s_par + g*8 + 4); // db,exy,exx,ezz
        float a0=0.f, a1=0.f, a2=0.f, a3=0.f;
        #pragma unroll
        for (int j = 0; j < KP; j++) {
            // cylinder
            a0 += __builtin_amdgcn_exp2f(xy2[j] * pA.x);
            // cone
            float d = __builtin_fmaf(-pA.y, zz[j], rxy[j]);
            a1 += __builtin_amdgcn_exp2f(d*d * pA.z);
            // disk
            a2 += __builtin_amdgcn_exp2f(__builtin_fmaf(xy2[j], pA.w, z2[j]*pB.x));
            // ellipsoid
            a3 += __builtin_amdgcn_exp2f(__builtin_fmaf(xy2[j], pB.y,
                          __builtin_fmaf(x2[j], pB.z, z2[j]*pB.w)));
        }
        // allreduce the 4 kind-partials across the 8 lanes of this query
        a0 += __shfl_xor(a0,1); a0 += __shfl_xor(a0,2); a0 += __shfl_xor(a0,4);
        a1 += __shfl_xor(a1,1); a1 += __shfl_xor(a1,2); a1 += __shfl_xor(a1,4);
        a2 += __shfl_xor(a2,1); a2 += __shfl_xor(a2,2); a2 += __shfl_xor(a2,4);
        a3 += __shfl_xor(a3,1); a3 += __shfl_xor(a3,2); a3 += __shfl_xor(a3,4);
        // fold lambda for this thread's 2 output columns immediately
        float2 l;
        l = lamp[(      g)*8]; o0 = __builtin_fmaf(a0,l.x,o0); o1 = __builtin_fmaf(a0,l.y,o1);
        l = lamp[(G   + g)*8]; o0 = __builtin_fmaf(a1,l.x,o0); o1 = __builtin_fmaf(a1,l.y,o1);
        l = lamp[(2*G + g)*8]; o0 = __builtin_fmaf(a2,l.x,o0); o1 = __builtin_fmaf(a2,l.y,o1);
        l = lamp[(3*G + g)*8]; o0 = __builtin_fmaf(a3,l.x,o0); o1 = __builtin_fmaf(a3,l.y,o1);
    }

    const float s = 1.0f / (float)KNBR;
    *(float2*)(out + (size_t)m * OBS + sub*2) = make_float2(o0*s, o1*s);
}

extern "C" void kernel_launch(void* const* d_in, const int* in_sizes, int n_in,
                              void* d_out, int out_size, void* d_ws, size_t ws_size,
                              hipStream_t stream) {
    const float* points      = (const float*)d_in[0];
    const float* q_coords    = (const float*)d_in[1];
    const int*   sidx        = (const int*)  d_in[2];
    const float* cy_radius   = (const float*)d_in[3];
    const float* disk_radius = (const float*)d_in[4];
    const float* disk_width  = (const float*)d_in[5];
    const float* cone_radius = (const float*)d_in[6];
    const float* cone_inc    = (const float*)d_in[7];
    const float* ellip_radii = (const float*)d_in[8];
    const float* lambdas     = (const float*)d_in[9];
    float* out = (float*)d_out;

    const int M = in_sizes[1] / 3;
    const int grid = (M * TPQ + BLOCK - 1) / BLOCK;
    gib_kernel<<<grid, BLOCK, 0, stream>>>(points, q_coords, sidx,
                                           cy_radius, disk_radius, disk_width,
                                           cone_radius, cone_inc, ellip_radii,
                                           lambdas, out, M);
}